// Round 5
// baseline (424.842 us; speedup 1.0000x reference)
//
#include <hip/hip_runtime.h>

#define N_NODES 100000
#define N_EDGES 1600000
#define IN_CH 256
#define HID_CH 128
#define SCAN_BLOCKS ((N_NODES + 255) / 256)   // 391

typedef __attribute__((ext_vector_type(8))) short short8;
typedef __attribute__((ext_vector_type(4))) float floatx4;

// fp32 -> bf16 round-to-nearest-even
static __device__ __forceinline__ unsigned short f2bf(float f) {
    unsigned int u = __float_as_uint(f);
    u += 0x7fffu + ((u >> 16) & 1u);
    return (unsigned short)(u >> 16);
}
static __device__ __forceinline__ unsigned pk(float a, float b) {
    return (unsigned)f2bf(a) | ((unsigned)f2bf(b) << 16);
}

// ---------------- CSR build ----------------

__global__ void count_kernel(const int* __restrict__ dst, int* __restrict__ counts,
                             int* __restrict__ rank) {
    int e = blockIdx.x * blockDim.x + threadIdx.x;
    if (e < N_EDGES) rank[e] = atomicAdd(&counts[dst[e]], 1);
}

__global__ void scanA_kernel(const int* __restrict__ counts, int* __restrict__ row_start,
                             int* __restrict__ partials) {
    __shared__ int ss[256];
    int tid = threadIdx.x;
    int i = blockIdx.x * 256 + tid;
    int v = (i < N_NODES) ? counts[i] : 0;
    ss[tid] = v;
    __syncthreads();
    for (int off = 1; off < 256; off <<= 1) {
        int t = (tid >= off) ? ss[tid - off] : 0;
        __syncthreads();
        ss[tid] += t;
        __syncthreads();
    }
    if (i < N_NODES) row_start[i] = ss[tid] - v;
    if (tid == 255) partials[blockIdx.x] = ss[255];
}

__global__ void scanB_kernel(int* __restrict__ partials) {
    __shared__ int ss[512];
    int tid = threadIdx.x;
    int v = (tid < SCAN_BLOCKS) ? partials[tid] : 0;
    ss[tid] = v;
    __syncthreads();
    for (int off = 1; off < 512; off <<= 1) {
        int t = (tid >= off) ? ss[tid - off] : 0;
        __syncthreads();
        ss[tid] += t;
        __syncthreads();
    }
    if (tid < SCAN_BLOCKS) partials[tid] = ss[tid] - v;
}

__global__ void scanC_kernel(int* __restrict__ row_start, const int* __restrict__ partials,
                             const int* __restrict__ counts, float* __restrict__ dinv) {
    int i = blockIdx.x * 256 + threadIdx.x;
    if (i >= N_NODES) return;
    row_start[i] += partials[blockIdx.x];
    dinv[i] = rsqrtf((float)(counts[i] + 1));   // +1 self loop
    if (i == 0) row_start[N_NODES] = N_EDGES;
}

__global__ void reorder_kernel(const int* __restrict__ ei, const int* __restrict__ rank,
                               const int* __restrict__ row_start, int* __restrict__ sorted) {
    int e = blockIdx.x * blockDim.x + threadIdx.x;
    if (e >= N_EDGES) return;
    int dst = ei[N_EDGES + e];
    int pos = row_start[dst] + rank[e];
    __builtin_nontemporal_store(ei[e], &sorted[pos]);
}

// ---------------- W^T -> bf16 ----------------

__global__ void wt_kernel(const float* __restrict__ W, unsigned short* __restrict__ Wt) {
    int i = blockIdx.x * blockDim.x + threadIdx.x;
    if (i >= IN_CH * HID_CH) return;
    int k = i >> 7;
    int c = i & 127;
    Wt[c * IN_CH + k] = f2bf(W[i]);
}

// ---------------- MFMA GEMM: hp = bf16( dinv[row] * (x @ W) ), permuted ----------------
// One wave = 32 rows (2 row-tiles) x 128 cols. B-frags shared by both tiles.
// hp channel layout PERMUTED: true channel t*16+m stored at position m*8+t,
// so each lane stores one contiguous uint4 per output row.

__launch_bounds__(256)
__global__ void gemm_mfma_kernel(const float* __restrict__ x,
                                 const unsigned short* __restrict__ Wt,
                                 const float* __restrict__ dinv,
                                 unsigned short* __restrict__ hp) {
    int gwave = (blockIdx.x * blockDim.x + threadIdx.x) >> 6;
    int lane = threadIdx.x & 63;
    if (gwave >= N_NODES / 32) return;   // 100000 = 32 * 3125 exactly
    int row0 = gwave * 32;

    int m = lane & 15;
    int q = lane >> 4;

    const float* xp0 = &x[(size_t)(row0 + m) * IN_CH + q * 8];
    const float* xp1 = &x[(size_t)(row0 + 16 + m) * IN_CH + q * 8];

    floatx4 acc[2][8];
#pragma unroll
    for (int r = 0; r < 2; ++r)
#pragma unroll
        for (int t = 0; t < 8; ++t) acc[r][t] = (floatx4){0.f, 0.f, 0.f, 0.f};

#pragma unroll
    for (int k0 = 0; k0 < IN_CH; k0 += 32) {
        float4 a00 = *(const float4*)(xp0 + k0);
        float4 a01 = *(const float4*)(xp0 + k0 + 4);
        float4 a10 = *(const float4*)(xp1 + k0);
        float4 a11 = *(const float4*)(xp1 + k0 + 4);
        short8 af0, af1;
        af0[0] = (short)f2bf(a00.x); af0[1] = (short)f2bf(a00.y);
        af0[2] = (short)f2bf(a00.z); af0[3] = (short)f2bf(a00.w);
        af0[4] = (short)f2bf(a01.x); af0[5] = (short)f2bf(a01.y);
        af0[6] = (short)f2bf(a01.z); af0[7] = (short)f2bf(a01.w);
        af1[0] = (short)f2bf(a10.x); af1[1] = (short)f2bf(a10.y);
        af1[2] = (short)f2bf(a10.z); af1[3] = (short)f2bf(a10.w);
        af1[4] = (short)f2bf(a11.x); af1[5] = (short)f2bf(a11.y);
        af1[6] = (short)f2bf(a11.z); af1[7] = (short)f2bf(a11.w);
#pragma unroll
        for (int t = 0; t < 8; ++t) {
            short8 bf = *(const short8*)&Wt[(size_t)(t * 16 + m) * IN_CH + k0 + q * 8];
            acc[0][t] = __builtin_amdgcn_mfma_f32_16x16x32_bf16(af0, bf, acc[0][t], 0, 0, 0);
            acc[1][t] = __builtin_amdgcn_mfma_f32_16x16x32_bf16(af1, bf, acc[1][t], 0, 0, 0);
        }
    }

    // C/D: row(M)=q*4+reg, col(N within tile t)=m. True channel = t*16+m,
    // stored at permuted position m*8+t => one contiguous uint4 per lane/row.
#pragma unroll
    for (int r = 0; r < 2; ++r)
#pragma unroll
        for (int reg = 0; reg < 4; ++reg) {
            int grow = row0 + r * 16 + q * 4 + reg;
            float di = dinv[grow];
            uint4 u;
            u.x = pk(acc[r][0][reg] * di, acc[r][1][reg] * di);
            u.y = pk(acc[r][2][reg] * di, acc[r][3][reg] * di);
            u.z = pk(acc[r][4][reg] * di, acc[r][5][reg] * di);
            u.w = pk(acc[r][6][reg] * di, acc[r][7][reg] * di);
            *(uint4*)&hp[(size_t)grow * HID_CH + m * 8] = u;
        }
}

// ---------------- gather + finalize ----------------
// One wave per node; 4 parts x unroll 2 = 8 hp-rows in flight.
// Direct index loads (NO cross-lane ops in divergent regions — round-4 bug).

__launch_bounds__(256)
__global__ void gather_finalize_kernel(const int* __restrict__ row_start,
                                       const int* __restrict__ sorted,
                                       const float* __restrict__ dinv,
                                       const unsigned short* __restrict__ hp,
                                       const float* __restrict__ bias,
                                       const float* __restrict__ alpha,
                                       float* __restrict__ out) {
    int node = (blockIdx.x * blockDim.x + threadIdx.x) >> 6;
    int lane = threadIdx.x & 63;
    if (node >= N_NODES) return;

    int beg = row_start[node];
    int endv = row_start[node + 1];
    int part = lane >> 4;
    int ch = (lane & 15) * 8;    // permuted position

    float acc[8];
#pragma unroll
    for (int i = 0; i < 8; ++i) acc[i] = 0.f;

    int j = beg + part;
    for (; j + 4 < endv; j += 8) {
        int s1 = sorted[j];
        int s2 = sorted[j + 4];
        uint4 u1 = *(const uint4*)&hp[(size_t)s1 * HID_CH + ch];
        uint4 u2 = *(const uint4*)&hp[(size_t)s2 * HID_CH + ch];
        acc[0] += __uint_as_float(u1.x << 16);
        acc[1] += __uint_as_float(u1.x & 0xffff0000u);
        acc[2] += __uint_as_float(u1.y << 16);
        acc[3] += __uint_as_float(u1.y & 0xffff0000u);
        acc[4] += __uint_as_float(u1.z << 16);
        acc[5] += __uint_as_float(u1.z & 0xffff0000u);
        acc[6] += __uint_as_float(u1.w << 16);
        acc[7] += __uint_as_float(u1.w & 0xffff0000u);
        acc[0] += __uint_as_float(u2.x << 16);
        acc[1] += __uint_as_float(u2.x & 0xffff0000u);
        acc[2] += __uint_as_float(u2.y << 16);
        acc[3] += __uint_as_float(u2.y & 0xffff0000u);
        acc[4] += __uint_as_float(u2.z << 16);
        acc[5] += __uint_as_float(u2.z & 0xffff0000u);
        acc[6] += __uint_as_float(u2.w << 16);
        acc[7] += __uint_as_float(u2.w & 0xffff0000u);
    }
    if (j < endv) {
        int s = sorted[j];
        uint4 u = *(const uint4*)&hp[(size_t)s * HID_CH + ch];
        acc[0] += __uint_as_float(u.x << 16);
        acc[1] += __uint_as_float(u.x & 0xffff0000u);
        acc[2] += __uint_as_float(u.y << 16);
        acc[3] += __uint_as_float(u.y & 0xffff0000u);
        acc[4] += __uint_as_float(u.z << 16);
        acc[5] += __uint_as_float(u.z & 0xffff0000u);
        acc[6] += __uint_as_float(u.w << 16);
        acc[7] += __uint_as_float(u.w & 0xffff0000u);
    }

    // all lanes converged here; butterfly over the 4 parts
#pragma unroll
    for (int i = 0; i < 8; ++i) {
        acc[i] += __shfl_xor(acc[i], 16);
        acc[i] += __shfl_xor(acc[i], 32);
    }

    if (part == 0) {
        float di = dinv[node];
        int mm = lane & 15;
        uint4 us = *(const uint4*)&hp[(size_t)node * HID_CH + ch];
        float sf[8];
        sf[0] = __uint_as_float(us.x << 16);
        sf[1] = __uint_as_float(us.x & 0xffff0000u);
        sf[2] = __uint_as_float(us.y << 16);
        sf[3] = __uint_as_float(us.y & 0xffff0000u);
        sf[4] = __uint_as_float(us.z << 16);
        sf[5] = __uint_as_float(us.z & 0xffff0000u);
        sf[6] = __uint_as_float(us.w << 16);
        sf[7] = __uint_as_float(us.w & 0xffff0000u);

        // permuted position mm*8+t holds TRUE channel t*16+mm
#pragma unroll
        for (int t = 0; t < 8; ++t) {
            int c = t * 16 + mm;
            float v = di * (acc[t] + sf[t]) + bias[c];
            out[(size_t)node * HID_CH + c] = v > 0.f ? v : alpha[c] * v;
        }
    }
}

// ---------------- launch ----------------

extern "C" void kernel_launch(void* const* d_in, const int* in_sizes, int n_in,
                              void* d_out, int out_size, void* d_ws, size_t ws_size,
                              hipStream_t stream) {
    const float* x     = (const float*)d_in[0];
    const int*   ei    = (const int*)d_in[1];     // [2, E]: [0..E)=src, [E..2E)=dst
    const float* W     = (const float*)d_in[2];
    const float* bias  = (const float*)d_in[3];
    const float* alpha = (const float*)d_in[4];
    float* out = (float*)d_out;

    char* p = (char*)d_ws;
    auto align512 = [](size_t v) { return (v + 511) / 512 * 512; };
    unsigned short* hp = (unsigned short*)p; p += align512((size_t)N_NODES * HID_CH * 2);
    unsigned short* Wt = (unsigned short*)p; p += align512((size_t)IN_CH * HID_CH * 2);
    int* counts    = (int*)p;   p += align512((size_t)N_NODES * 4);
    float* dinv    = (float*)p; p += align512((size_t)N_NODES * 4);
    int* row_start = (int*)p;   p += align512((size_t)(N_NODES + 1) * 4);
    int* rank      = (int*)p;   p += align512((size_t)N_EDGES * 4);
    int* partials  = (int*)p;   p += align512(512 * 4);
    int* sorted    = (int*)p;   p += align512((size_t)N_EDGES * 4);

    hipMemsetAsync(counts, 0, (size_t)N_NODES * sizeof(int), stream);

    count_kernel<<<(N_EDGES + 255) / 256, 256, 0, stream>>>(ei + N_EDGES, counts, rank);
    scanA_kernel<<<SCAN_BLOCKS, 256, 0, stream>>>(counts, row_start, partials);
    scanB_kernel<<<1, 512, 0, stream>>>(partials);
    scanC_kernel<<<SCAN_BLOCKS, 256, 0, stream>>>(row_start, partials, counts, dinv);
    reorder_kernel<<<(N_EDGES + 255) / 256, 256, 0, stream>>>(ei, rank, row_start, sorted);

    wt_kernel<<<(IN_CH * HID_CH + 255) / 256, 256, 0, stream>>>(W, Wt);

    long long gemm_threads = (long long)(N_NODES / 32) * 64;
    gemm_mfma_kernel<<<(int)((gemm_threads + 255) / 256), 256, 0, stream>>>(x, Wt, dinv, hp);

    long long gthreads = (long long)N_NODES * 64;
    gather_finalize_kernel<<<(int)((gthreads + 255) / 256), 256, 0, stream>>>(
        row_start, sorted, dinv, hp, bias, alpha, out);
}

// Round 6
// 410.738 us; speedup vs baseline: 1.0343x; 1.0343x over previous
//
#include <hip/hip_runtime.h>

#define N_NODES 100000
#define N_EDGES 1600000
#define IN_CH 256
#define HID_CH 128
#define SCAN_BLOCKS ((N_NODES + 255) / 256)   // 391

typedef __attribute__((ext_vector_type(8))) short short8;
typedef __attribute__((ext_vector_type(4))) float floatx4;

// fp32 -> bf16 round-to-nearest-even
static __device__ __forceinline__ unsigned short f2bf(float f) {
    unsigned int u = __float_as_uint(f);
    u += 0x7fffu + ((u >> 16) & 1u);
    return (unsigned short)(u >> 16);
}
static __device__ __forceinline__ unsigned pk(float a, float b) {
    return (unsigned)f2bf(a) | ((unsigned)f2bf(b) << 16);
}

// ---------------- CSR build ----------------

__global__ void count_kernel(const int* __restrict__ dst, int* __restrict__ counts,
                             int* __restrict__ rank) {
    int e = blockIdx.x * blockDim.x + threadIdx.x;
    if (e < N_EDGES) rank[e] = atomicAdd(&counts[dst[e]], 1);
}

__global__ void scanA_kernel(const int* __restrict__ counts, int* __restrict__ row_start,
                             int* __restrict__ partials) {
    __shared__ int ss[256];
    int tid = threadIdx.x;
    int i = blockIdx.x * 256 + tid;
    int v = (i < N_NODES) ? counts[i] : 0;
    ss[tid] = v;
    __syncthreads();
    for (int off = 1; off < 256; off <<= 1) {
        int t = (tid >= off) ? ss[tid - off] : 0;
        __syncthreads();
        ss[tid] += t;
        __syncthreads();
    }
    if (i < N_NODES) row_start[i] = ss[tid] - v;
    if (tid == 255) partials[blockIdx.x] = ss[255];
}

__global__ void scanB_kernel(int* __restrict__ partials) {
    __shared__ int ss[512];
    int tid = threadIdx.x;
    int v = (tid < SCAN_BLOCKS) ? partials[tid] : 0;
    ss[tid] = v;
    __syncthreads();
    for (int off = 1; off < 512; off <<= 1) {
        int t = (tid >= off) ? ss[tid - off] : 0;
        __syncthreads();
        ss[tid] += t;
        __syncthreads();
    }
    if (tid < SCAN_BLOCKS) partials[tid] = ss[tid] - v;
}

__global__ void scanC_kernel(int* __restrict__ row_start, const int* __restrict__ partials,
                             const int* __restrict__ counts, float* __restrict__ dinv) {
    int i = blockIdx.x * 256 + threadIdx.x;
    if (i >= N_NODES) return;
    row_start[i] += partials[blockIdx.x];
    dinv[i] = rsqrtf((float)(counts[i] + 1));   // +1 self loop
    if (i == 0) row_start[N_NODES] = N_EDGES;
}

// plain store: L2 absorbs/merges the 4B scatter, and keeps `sorted` L2-hot
// for the gather's index loads (NT store here cost ~25% on gather — round 5).
__global__ void reorder_kernel(const int* __restrict__ ei, const int* __restrict__ rank,
                               const int* __restrict__ row_start, int* __restrict__ sorted) {
    int e = blockIdx.x * blockDim.x + threadIdx.x;
    if (e >= N_EDGES) return;
    int dst = ei[N_EDGES + e];
    sorted[row_start[dst] + rank[e]] = ei[e];
}

// ---------------- W^T -> bf16 ----------------

__global__ void wt_kernel(const float* __restrict__ W, unsigned short* __restrict__ Wt) {
    int i = blockIdx.x * blockDim.x + threadIdx.x;
    if (i >= IN_CH * HID_CH) return;
    int k = i >> 7;
    int c = i & 127;
    Wt[c * IN_CH + k] = f2bf(W[i]);
}

// ---------------- MFMA GEMM: hp = bf16( dinv[row] * (x @ W) ), permuted ----------------
// One wave = 32 rows (2 row-tiles) x 128 cols. B-frags shared by both tiles.
// hp channel layout PERMUTED: true channel t*16+m stored at position m*8+t,
// so each lane stores one contiguous uint4 per output row.

__launch_bounds__(256)
__global__ void gemm_mfma_kernel(const float* __restrict__ x,
                                 const unsigned short* __restrict__ Wt,
                                 const float* __restrict__ dinv,
                                 unsigned short* __restrict__ hp) {
    int gwave = (blockIdx.x * blockDim.x + threadIdx.x) >> 6;
    int lane = threadIdx.x & 63;
    if (gwave >= N_NODES / 32) return;   // 100000 = 32 * 3125 exactly
    int row0 = gwave * 32;

    int m = lane & 15;
    int q = lane >> 4;

    const float* xp0 = &x[(size_t)(row0 + m) * IN_CH + q * 8];
    const float* xp1 = &x[(size_t)(row0 + 16 + m) * IN_CH + q * 8];

    floatx4 acc[2][8];
#pragma unroll
    for (int r = 0; r < 2; ++r)
#pragma unroll
        for (int t = 0; t < 8; ++t) acc[r][t] = (floatx4){0.f, 0.f, 0.f, 0.f};

#pragma unroll
    for (int k0 = 0; k0 < IN_CH; k0 += 32) {
        float4 a00 = *(const float4*)(xp0 + k0);
        float4 a01 = *(const float4*)(xp0 + k0 + 4);
        float4 a10 = *(const float4*)(xp1 + k0);
        float4 a11 = *(const float4*)(xp1 + k0 + 4);
        short8 af0, af1;
        af0[0] = (short)f2bf(a00.x); af0[1] = (short)f2bf(a00.y);
        af0[2] = (short)f2bf(a00.z); af0[3] = (short)f2bf(a00.w);
        af0[4] = (short)f2bf(a01.x); af0[5] = (short)f2bf(a01.y);
        af0[6] = (short)f2bf(a01.z); af0[7] = (short)f2bf(a01.w);
        af1[0] = (short)f2bf(a10.x); af1[1] = (short)f2bf(a10.y);
        af1[2] = (short)f2bf(a10.z); af1[3] = (short)f2bf(a10.w);
        af1[4] = (short)f2bf(a11.x); af1[5] = (short)f2bf(a11.y);
        af1[6] = (short)f2bf(a11.z); af1[7] = (short)f2bf(a11.w);
#pragma unroll
        for (int t = 0; t < 8; ++t) {
            short8 bf = *(const short8*)&Wt[(size_t)(t * 16 + m) * IN_CH + k0 + q * 8];
            acc[0][t] = __builtin_amdgcn_mfma_f32_16x16x32_bf16(af0, bf, acc[0][t], 0, 0, 0);
            acc[1][t] = __builtin_amdgcn_mfma_f32_16x16x32_bf16(af1, bf, acc[1][t], 0, 0, 0);
        }
    }

    // C/D: row(M)=q*4+reg, col(N within tile t)=m. True channel = t*16+m,
    // stored at permuted position m*8+t => one contiguous uint4 per lane/row.
#pragma unroll
    for (int r = 0; r < 2; ++r)
#pragma unroll
        for (int reg = 0; reg < 4; ++reg) {
            int grow = row0 + r * 16 + q * 4 + reg;
            float di = dinv[grow];
            uint4 u;
            u.x = pk(acc[r][0][reg] * di, acc[r][1][reg] * di);
            u.y = pk(acc[r][2][reg] * di, acc[r][3][reg] * di);
            u.z = pk(acc[r][4][reg] * di, acc[r][5][reg] * di);
            u.w = pk(acc[r][6][reg] * di, acc[r][7][reg] * di);
            *(uint4*)&hp[(size_t)grow * HID_CH + m * 8] = u;
        }
}

// ---------------- gather + finalize ----------------
// One wave per node; 4 parts x unroll 2 = 8 hp-rows in flight.
// Direct index loads (NO cross-lane ops in divergent regions — round-4 bug).

__launch_bounds__(256)
__global__ void gather_finalize_kernel(const int* __restrict__ row_start,
                                       const int* __restrict__ sorted,
                                       const float* __restrict__ dinv,
                                       const unsigned short* __restrict__ hp,
                                       const float* __restrict__ bias,
                                       const float* __restrict__ alpha,
                                       float* __restrict__ out) {
    int node = (blockIdx.x * blockDim.x + threadIdx.x) >> 6;
    int lane = threadIdx.x & 63;
    if (node >= N_NODES) return;

    int beg = row_start[node];
    int endv = row_start[node + 1];
    int part = lane >> 4;
    int ch = (lane & 15) * 8;    // permuted position

    float acc[8];
#pragma unroll
    for (int i = 0; i < 8; ++i) acc[i] = 0.f;

    int j = beg + part;
    for (; j + 4 < endv; j += 8) {
        int s1 = sorted[j];
        int s2 = sorted[j + 4];
        uint4 u1 = *(const uint4*)&hp[(size_t)s1 * HID_CH + ch];
        uint4 u2 = *(const uint4*)&hp[(size_t)s2 * HID_CH + ch];
        acc[0] += __uint_as_float(u1.x << 16);
        acc[1] += __uint_as_float(u1.x & 0xffff0000u);
        acc[2] += __uint_as_float(u1.y << 16);
        acc[3] += __uint_as_float(u1.y & 0xffff0000u);
        acc[4] += __uint_as_float(u1.z << 16);
        acc[5] += __uint_as_float(u1.z & 0xffff0000u);
        acc[6] += __uint_as_float(u1.w << 16);
        acc[7] += __uint_as_float(u1.w & 0xffff0000u);
        acc[0] += __uint_as_float(u2.x << 16);
        acc[1] += __uint_as_float(u2.x & 0xffff0000u);
        acc[2] += __uint_as_float(u2.y << 16);
        acc[3] += __uint_as_float(u2.y & 0xffff0000u);
        acc[4] += __uint_as_float(u2.z << 16);
        acc[5] += __uint_as_float(u2.z & 0xffff0000u);
        acc[6] += __uint_as_float(u2.w << 16);
        acc[7] += __uint_as_float(u2.w & 0xffff0000u);
    }
    if (j < endv) {
        int s = sorted[j];
        uint4 u = *(const uint4*)&hp[(size_t)s * HID_CH + ch];
        acc[0] += __uint_as_float(u.x << 16);
        acc[1] += __uint_as_float(u.x & 0xffff0000u);
        acc[2] += __uint_as_float(u.y << 16);
        acc[3] += __uint_as_float(u.y & 0xffff0000u);
        acc[4] += __uint_as_float(u.z << 16);
        acc[5] += __uint_as_float(u.z & 0xffff0000u);
        acc[6] += __uint_as_float(u.w << 16);
        acc[7] += __uint_as_float(u.w & 0xffff0000u);
    }

    // all lanes converged here; butterfly over the 4 parts
#pragma unroll
    for (int i = 0; i < 8; ++i) {
        acc[i] += __shfl_xor(acc[i], 16);
        acc[i] += __shfl_xor(acc[i], 32);
    }

    if (part == 0) {
        float di = dinv[node];
        int mm = lane & 15;
        uint4 us = *(const uint4*)&hp[(size_t)node * HID_CH + ch];
        float sf[8];
        sf[0] = __uint_as_float(us.x << 16);
        sf[1] = __uint_as_float(us.x & 0xffff0000u);
        sf[2] = __uint_as_float(us.y << 16);
        sf[3] = __uint_as_float(us.y & 0xffff0000u);
        sf[4] = __uint_as_float(us.z << 16);
        sf[5] = __uint_as_float(us.z & 0xffff0000u);
        sf[6] = __uint_as_float(us.w << 16);
        sf[7] = __uint_as_float(us.w & 0xffff0000u);

        // permuted position mm*8+t holds TRUE channel t*16+mm
#pragma unroll
        for (int t = 0; t < 8; ++t) {
            int c = t * 16 + mm;
            float v = di * (acc[t] + sf[t]) + bias[c];
            out[(size_t)node * HID_CH + c] = v > 0.f ? v : alpha[c] * v;
        }
    }
}

// ---------------- launch ----------------

extern "C" void kernel_launch(void* const* d_in, const int* in_sizes, int n_in,
                              void* d_out, int out_size, void* d_ws, size_t ws_size,
                              hipStream_t stream) {
    const float* x     = (const float*)d_in[0];
    const int*   ei    = (const int*)d_in[1];     // [2, E]: [0..E)=src, [E..2E)=dst
    const float* W     = (const float*)d_in[2];
    const float* bias  = (const float*)d_in[3];
    const float* alpha = (const float*)d_in[4];
    float* out = (float*)d_out;

    char* p = (char*)d_ws;
    auto align512 = [](size_t v) { return (v + 511) / 512 * 512; };
    unsigned short* hp = (unsigned short*)p; p += align512((size_t)N_NODES * HID_CH * 2);
    unsigned short* Wt = (unsigned short*)p; p += align512((size_t)IN_CH * HID_CH * 2);
    int* counts    = (int*)p;   p += align512((size_t)N_NODES * 4);
    float* dinv    = (float*)p; p += align512((size_t)N_NODES * 4);
    int* row_start = (int*)p;   p += align512((size_t)(N_NODES + 1) * 4);
    int* rank      = (int*)p;   p += align512((size_t)N_EDGES * 4);
    int* partials  = (int*)p;   p += align512(512 * 4);
    int* sorted    = (int*)p;   p += align512((size_t)N_EDGES * 4);

    hipMemsetAsync(counts, 0, (size_t)N_NODES * sizeof(int), stream);

    count_kernel<<<(N_EDGES + 255) / 256, 256, 0, stream>>>(ei + N_EDGES, counts, rank);
    scanA_kernel<<<SCAN_BLOCKS, 256, 0, stream>>>(counts, row_start, partials);
    scanB_kernel<<<1, 512, 0, stream>>>(partials);
    scanC_kernel<<<SCAN_BLOCKS, 256, 0, stream>>>(row_start, partials, counts, dinv);
    reorder_kernel<<<(N_EDGES + 255) / 256, 256, 0, stream>>>(ei, rank, row_start, sorted);

    wt_kernel<<<(IN_CH * HID_CH + 255) / 256, 256, 0, stream>>>(W, Wt);

    long long gemm_threads = (long long)(N_NODES / 32) * 64;
    gemm_mfma_kernel<<<(int)((gemm_threads + 255) / 256), 256, 0, stream>>>(x, Wt, dinv, hp);

    long long gthreads = (long long)N_NODES * 64;
    gather_finalize_kernel<<<(int)((gthreads + 255) / 256), 256, 0, stream>>>(
        row_start, sorted, dinv, hp, bias, alpha, out);
}